// Round 1
// baseline (1476.791 us; speedup 1.0000x reference)
//
#include <hip/hip_runtime.h>
#include <math.h>

#define TS 10
#define TD 128
#define TE 64
#define BT 8
#define NTHR 256
#define HSTR 132          // floats per Hs row (pad: breaks bank alignment, keeps 16B align)
#define QSTR 68           // floats per Q/K/Vd/G/t row
#define NHROWS (TS*BT)    // 80

#define HS_FLOATS (NHROWS*HSTR)    // 10560
#define BUF_FLOATS (40*QSTR)       // 2720 (half-batch 40 rows)
#define P_FLOATS (BT*TS*12)        // 960
#define LDS_FLOATS (HS_FLOATS + 3*BUF_FLOATS + P_FLOATS)   // 19680 -> 78720 B

#define INVSQRT10 0.31622776601683794f

// ---------------- POS precompute (fp64, once per launch, into d_ws) ----------
__global__ void pos_kernel(float* __restrict__ pos) {
    for (int idx = threadIdx.x; idx < TS * TD; idx += blockDim.x) {
        int n = idx / TD, d = idx % TD;
        int j = d >> 1;
        double ang = (double)n / pow(1000.0, 2.0 * (double)j / (double)TD);
        double v = (d & 1) ? cos(ang) : sin(ang);
        pos[idx] = (float)v;
    }
}

// ---------------- generic 4-row x 8-col GEMM tile ---------------------------
// OUT[m][c] (4x8) = sum_k A[a0 + m*astr + k] * W[k*ws + c],  k in [0,K)
// A, O are LDS float*; W is global float* pre-offset to col0.
template <int K, typename ACC>
__device__ __forceinline__ void gemm4x8(
    const float* __restrict__ Ap, int a0, int astr,
    const float* __restrict__ W, int ws,
    float* __restrict__ Op, int o0, int ostr,
    float scale, bool add)
{
    ACC acc[4][8];
#pragma unroll
    for (int m = 0; m < 4; m++)
#pragma unroll
        for (int c = 0; c < 8; c++) acc[m][c] = (ACC)0;

    for (int k = 0; k < K; k += 4) {
        float4 va[4];
#pragma unroll
        for (int m = 0; m < 4; m++)
            va[m] = *(const float4*)(Ap + a0 + m * astr + k);
        float wv[4][8];
#pragma unroll
        for (int kk = 0; kk < 4; kk++) {
            float4 wa = *(const float4*)(W + (size_t)(k + kk) * ws);
            float4 wb = *(const float4*)(W + (size_t)(k + kk) * ws + 4);
            wv[kk][0] = wa.x; wv[kk][1] = wa.y; wv[kk][2] = wa.z; wv[kk][3] = wa.w;
            wv[kk][4] = wb.x; wv[kk][5] = wb.y; wv[kk][6] = wb.z; wv[kk][7] = wb.w;
        }
#pragma unroll
        for (int m = 0; m < 4; m++) {
            float am[4];
            am[0] = va[m].x; am[1] = va[m].y; am[2] = va[m].z; am[3] = va[m].w;
#pragma unroll
            for (int kk = 0; kk < 4; kk++)
#pragma unroll
                for (int c = 0; c < 8; c++) {
                    if constexpr (sizeof(ACC) == 8)
                        acc[m][c] = fma((double)am[kk], (double)wv[kk][c], acc[m][c]);
                    else
                        acc[m][c] = fmaf(am[kk], wv[kk][c], acc[m][c]);
                }
        }
    }
#pragma unroll
    for (int m = 0; m < 4; m++) {
        float* op = Op + o0 + m * ostr;
        if (add) {
            float4 v0 = *(float4*)op;
            float4 v1 = *((float4*)op + 1);
            v0.x = fmaf(scale, (float)acc[m][0], v0.x);
            v0.y = fmaf(scale, (float)acc[m][1], v0.y);
            v0.z = fmaf(scale, (float)acc[m][2], v0.z);
            v0.w = fmaf(scale, (float)acc[m][3], v0.w);
            v1.x = fmaf(scale, (float)acc[m][4], v1.x);
            v1.y = fmaf(scale, (float)acc[m][5], v1.y);
            v1.z = fmaf(scale, (float)acc[m][6], v1.z);
            v1.w = fmaf(scale, (float)acc[m][7], v1.w);
            *(float4*)op = v0;
            *((float4*)op + 1) = v1;
        } else {
            float4 v0, v1;
            v0.x = (float)acc[m][0]; v0.y = (float)acc[m][1];
            v0.z = (float)acc[m][2]; v0.w = (float)acc[m][3];
            v1.x = (float)acc[m][4]; v1.y = (float)acc[m][5];
            v1.z = (float)acc[m][6]; v1.w = (float)acc[m][7];
            *(float4*)op = v0;
            *((float4*)op + 1) = v1;
        }
    }
}

// ---------------- fused kernel ----------------------------------------------
extern "C" __global__ __launch_bounds__(NTHR, 2)
void trans_fused(const float* __restrict__ x,
                 const float* __restrict__ L_w, const float* __restrict__ UL_w,
                 const float* __restrict__ WQ,  const float* __restrict__ WK,
                 const float* __restrict__ WVd, const float* __restrict__ WVu,
                 const float* __restrict__ WQ2, const float* __restrict__ WK2,
                 const float* __restrict__ WVd2,const float* __restrict__ WVu2,
                 const float* __restrict__ qin1,const float* __restrict__ qout1,
                 const float* __restrict__ qin2,const float* __restrict__ qout2,
                 const float* __restrict__ POSb, float* __restrict__ out)
{
    extern __shared__ float lds[];
    float* Hs = lds;                      // [80][HSTR], row = b*10 + n
    float* Ab = lds + HS_FLOATS;          // [40][QSTR] Q-half / G / t(part1)
    float* Bb = Ab + BUF_FLOATS;          // [40][QSTR] K-half / t(part2)
    float* Cb = Bb + BUF_FLOATS;          // [40][QSTR] Vd-half
    float* Pb = Cb + BUF_FLOATS;          // [8][10][12] logits -> softmax weights

    const int tid = threadIdx.x;
    const int gb0 = blockIdx.x * BT;

    // ---- Phase 0: h = x @ L_w + POS (fp64 accum) ----
    for (int idx = tid; idx < NHROWS * TD; idx += NTHR) {
        int r = idx >> 7, d = idx & 127;
        int b = r / 10, n = r - b * 10;
        const float* xp = x + ((size_t)(gb0 + b) * TS + n) * 4;
        double acc = (double)POSb[n * TD + d];
#pragma unroll
        for (int c = 0; c < 4; c++)
            acc += (double)xp[c] * (double)L_w[c * TD + d];
        Hs[r * HSTR + d] = (float)acc;
    }
    __syncthreads();

    for (int layer = 0; layer < 2; ++layer) {
        const float* pWQ  = layer ? WQ2  : WQ;
        const float* pWK  = layer ? WK2  : WK;
        const float* pWVd = layer ? WVd2 : WVd;
        const float* pWVu = layer ? WVu2 : WVu;
        const float* pqin = layer ? qin2 : qin1;
        const float* pqou = layer ? qout2 : qout1;

        for (int hb = 0; hb < 2; ++hb) {
            // ---- QKV: Q/K/Vd[half] = Hs(half rows) @ W  (fp64 accum) ----
            // 240 tiles: p(3) x n(10) x cg(8). buffer row rr = n*4 + b4.
            if (tid < 240) {
                int p = tid / 80, t2 = tid % 80;
                int n = t2 >> 3, cg = t2 & 7;
                const float* Wp = (p == 0 ? pWQ : (p == 1 ? pWK : pWVd)) + cg * 8;
                float* Ob = (p == 0 ? Ab : (p == 1 ? Bb : Cb));
                int a0 = (hb * 40 + n) * HSTR;              // rows (hb*4+m)*10 + n
                int o0 = (n * 4) * QSTR + cg * 8;           // rr = n*4 + m
                gemm4x8<TD, double>(Hs, a0, 10 * HSTR, Wp, TE, Ob, o0, QSTR, 1.f, false);
            }
            __syncthreads();

            // ---- logits (fp64 dot): 220 tasks = 4 batches x 55 (i,j<=i) pairs ----
            if (tid < 220) {
                int b4 = tid / 55, pr = tid % 55;
                int i = 0, base = 0;
                while (pr >= base + i + 1) { base += i + 1; i++; }
                int j = pr - base;
                const float* qr = Ab + (i * 4 + b4) * QSTR;
                const float* kr = Bb + (j * 4 + b4) * QSTR;
                double acc = 0.0;
                for (int e = 0; e < TE; e += 4) {
                    float4 q4 = *(const float4*)(qr + e);
                    float4 k4 = *(const float4*)(kr + e);
                    acc = fma((double)q4.x, (double)k4.x, acc);
                    acc = fma((double)q4.y, (double)k4.y, acc);
                    acc = fma((double)q4.z, (double)k4.z, acc);
                    acc = fma((double)q4.w, (double)k4.w, acc);
                }
                int b = hb * 4 + b4;
                Pb[b * 120 + i * 12 + j] = (float)acc;
            }
            __syncthreads();

            // ---- softmax over keys j<=i (fp32, matches reference) ----
            if (tid < 40) {
                int b4 = tid / 10, i = tid % 10;
                int b = hb * 4 + b4;
                float* pr = Pb + b * 120 + i * 12;
                float m = pr[0];
#pragma unroll
                for (int j = 1; j < TS; j++) if (j <= i) m = fmaxf(m, pr[j]);
                float sum = 0.f;
#pragma unroll
                for (int j = 0; j < TS; j++) if (j <= i) { float e = expf(pr[j] - m); pr[j] = e; sum += e; }
#pragma unroll
                for (int j = 0; j < TS; j++) pr[j] = (j <= i) ? pr[j] / sum : 0.f;
            }
            __syncthreads();

            // ---- G[q,e] = sum_k P[k->q] * Vd[k,e]  (into Ab; Q dead) ----
            for (int oi = tid; oi < 40 * TE; oi += NTHR) {
                int rr = oi >> 6, e = oi & 63;
                int q = rr >> 2, b4 = rr & 3;
                int b = hb * 4 + b4;
                const float* pp = Pb + b * 120 + q * 12;
                float g = 0.f;
#pragma unroll
                for (int k = 0; k < TS; k++)
                    g = fmaf(pp[k], Cb[(k * 4 + b4) * QSTR + e], g);
                Ab[rr * QSTR + e] = g;
            }
            __syncthreads();

            // ---- DE: Hs(half) += (1/sqrt(10)) * G @ WVu ----
            if (tid < 160) {
                int q = tid >> 4, cg = tid & 15;
                int a0 = (q * 4) * QSTR;                      // G rows q*4 + m
                int o0 = (hb * 40 + q) * HSTR + cg * 8;       // Hs rows (hb*4+m)*10 + q
                gemm4x8<TE, float>(Ab, a0, QSTR, pWVu + cg * 8, TD,
                                   Hs, o0, 10 * HSTR, INVSQRT10, true);
            }
            __syncthreads();
        } // hb

        // ---- ques-in: t[80][64] = Hs @ quesin[n]  (t in Ab..Bb) ----
        if (tid < 160) {
            int rowg = tid >> 3, cg = tid & 7;     // rowg = bg*10 + n
            int bg = rowg / 10, n = rowg - bg * 10;
            int a0 = (bg * 40 + n) * HSTR;         // rows (bg*4+m)*10 + n
            int o0 = (bg * 40 + n) * QSTR + cg * 8;
            gemm4x8<TD, float>(Hs, a0, 10 * HSTR,
                               pqin + (size_t)n * TD * TE + cg * 8, TE,
                               Ab, o0, 10 * QSTR, 1.f, false);
        }
        __syncthreads();

        // ---- ques-out: Hs = t @ quesout[n]  (full overwrite) ----
        for (int tile = tid; tile < 320; tile += NTHR) {
            int rowg = tile >> 4, cg = tile & 15;  // rowg = bg*10 + n
            int bg = rowg / 10, n = rowg - bg * 10;
            int a0 = (bg * 40 + n) * QSTR;
            int o0 = (bg * 40 + n) * HSTR + cg * 8;
            gemm4x8<TE, float>(Ab, a0, 10 * QSTR,
                               pqou + (size_t)n * TE * TD + cg * 8, TD,
                               Hs, o0, 10 * HSTR, 1.f, false);
        }
        __syncthreads();
    } // layer

    // ---- out = Hs @ UL_w  ([80][4] per WG) ----
    for (int idx = tid; idx < NHROWS * 4; idx += NTHR) {
        int r = idx >> 2, c = idx & 3;
        int b = r / 10, n = r - b * 10;
        const float* hr = Hs + r * HSTR;
        float acc = 0.f;
        for (int d = 0; d < TD; d += 4) {
            float4 h4 = *(const float4*)(hr + d);
            acc = fmaf(h4.x, UL_w[(d + 0) * 4 + c], acc);
            acc = fmaf(h4.y, UL_w[(d + 1) * 4 + c], acc);
            acc = fmaf(h4.z, UL_w[(d + 2) * 4 + c], acc);
            acc = fmaf(h4.w, UL_w[(d + 3) * 4 + c], acc);
        }
        out[((size_t)(gb0 + b) * TS + n) * 4 + c] = acc;
    }
}

// ---------------- host launch -----------------------------------------------
extern "C" void kernel_launch(void* const* d_in, const int* in_sizes, int n_in,
                              void* d_out, int out_size, void* d_ws, size_t ws_size,
                              hipStream_t stream) {
    const float* x    = (const float*)d_in[0];
    const float* L_w  = (const float*)d_in[1];
    const float* UL_w = (const float*)d_in[2];
    const float* WQ   = (const float*)d_in[3];
    const float* WK   = (const float*)d_in[4];
    const float* WVd  = (const float*)d_in[5];
    const float* WVu  = (const float*)d_in[6];
    const float* WQ2  = (const float*)d_in[7];
    const float* WK2  = (const float*)d_in[8];
    const float* WVd2 = (const float*)d_in[9];
    const float* WVu2 = (const float*)d_in[10];
    const float* qin1 = (const float*)d_in[11];
    const float* qout1= (const float*)d_in[12];
    const float* qin2 = (const float*)d_in[13];
    const float* qout2= (const float*)d_in[14];
    float* out = (float*)d_out;
    float* POSb = (float*)d_ws;

    int B = in_sizes[0] / (TS * 4);
    size_t lds_bytes = (size_t)LDS_FLOATS * sizeof(float);

    // >64KB dynamic LDS: opt in defensively (no-op where not required)
    (void)hipFuncSetAttribute((const void*)trans_fused,
                              hipFuncAttributeMaxDynamicSharedMemorySize,
                              (int)lds_bytes);

    pos_kernel<<<dim3(1), dim3(256), 0, stream>>>(POSb);
    trans_fused<<<dim3(B / BT), dim3(NTHR), lds_bytes, stream>>>(
        x, L_w, UL_w, WQ, WK, WVd, WVu, WQ2, WK2, WVd2, WVu2,
        qin1, qout1, qin2, qout2, POSb, out);
}